// Round 4
// baseline (894.419 us; speedup 1.0000x reference)
//
#include <hip/hip_runtime.h>
#include <math.h>

// DifferentiableLassoSelector: B=65536, n=256, h=32.
// p = 6553.6 - Z^T y > 0 elementwise (~40 sigma margin) => projected-gradient
// QP stays at lam=0 exactly => y_hat = 0 exactly.
// Fast path: Chebyshev-moment factorization. tanh(W1[n,h]*x+b1[n,h]) expanded
// in T_k(x/X) (X=6.5, 28 terms); then Z^T y needs only h-independent moments
// S_k[n] = sum_b y_b T_k(x[b,n]/X)  (~58 VALU per (b,n) instead of ~352).
// Device-side certification: per-(n,h) truncation error from observed coeff
// tail; flag taken only if min_n(p~ - cert) >= 0 AND max|x| <= X. Otherwise
// the exact exp2-tanh fallback pipeline (flag-guarded stubs) runs.

#define NF 256
#define HID 32
#define BATCHN 65536
#define ALPHA_BF 6553.6f               // ALPHA * BATCH
#define JITTERF 1e-4f
#define QP_ITERS_N 500
#define K2C 2.8853900817779268f        // 2*log2(e): exp2(K2C*u) = e^{2u}
#define XFIX 6.5f
#define INVX (1.0f / 6.5f)
#define DDEG 28                        // poly degree (c_0..c_28)
#define NNODE 44                       // Chebyshev interpolation nodes

// ws float layout:
// 0: flagA | 1: Xobs(uint bits) | 2: Sy | 3: SyAbs | 4..63 pad
// 64:      S[256*28]            -> 7232
// 7232:    ptil[256]            -> 7488
// 7488:    cert[256]            -> 7744  (pad to 7808)
// 7808:    c[29][8192]          -> 245376   (approx path only)
// 245376:  w2eps[8192]          -> 253568
// fallback overlay (only live when flagA==0):
// 7808:    part[nblk][256] ; then part2[16384], p_exact[256], lam[256],
//          Q[65536], L[65536], Qe[65536]

#if __has_builtin(__builtin_amdgcn_exp2f)
__device__ __forceinline__ float fexp2(float x) { return __builtin_amdgcn_exp2f(x); }
#else
__device__ __forceinline__ float fexp2(float x) { return exp2f(x); }
#endif
#if __has_builtin(__builtin_amdgcn_rcpf)
__device__ __forceinline__ float frcp(float x) { return __builtin_amdgcn_rcpf(x); }
#else
__device__ __forceinline__ float frcp(float x) { return 1.0f / x; }
#endif

// ---------------- zero scratch header ---------------------------------------
__global__ __launch_bounds__(256) void zero_kernel(float* __restrict__ wsf)
{
  int i = blockIdx.x * 256 + threadIdx.x;
  if (i < 7424) wsf[i] = 0.f;
}

// ---------------- y sums (Sy, Sy_abs) ----------------------------------------
__global__ __launch_bounds__(256) void ysum_kernel(const float* __restrict__ y,
                                                   float* __restrict__ wsf)
{
  int t = threadIdx.x;
  int i = (blockIdx.x * 256 + t) * 4;         // 64 blocks x 256 x 4 = 65536
  float4 v = *reinterpret_cast<const float4*>(y + i);
  float s  = (v.x + v.y) + (v.z + v.w);
  float sa = (fabsf(v.x) + fabsf(v.y)) + (fabsf(v.z) + fabsf(v.w));
  #pragma unroll
  for (int m = 1; m < 64; m <<= 1) {
    s  += __shfl_xor(s, m);
    sa += __shfl_xor(sa, m);
  }
  __shared__ float ls[4], la[4];
  int w = t >> 6;
  if ((t & 63) == 0) { ls[w] = s; la[w] = sa; }
  __syncthreads();
  if (t == 0) {
    atomicAdd(&wsf[2], (ls[0] + ls[1]) + (ls[2] + ls[3]));
    atomicAdd(&wsf[3], (la[0] + la[1]) + (la[2] + la[3]));
  }
}

// ---------------- fused moments (blocks 0..2047) + coeffs (2048..2079) -------
__global__ __launch_bounds__(256, 4) void momentcoeff_kernel(
    const float* __restrict__ x, const float* __restrict__ y,
    const float* __restrict__ W1, const float* __restrict__ b1,
    const float* __restrict__ W2, float* __restrict__ wsf)
{
  const int t = threadIdx.x;
  float* S     = wsf + 64;
  float* cws   = wsf + 7808;
  float* w2eps = wsf + 245376;

  if (blockIdx.x < 2048) {
    // ---- moment path: thread = feature n; 32 rows per block ----
    const int n = t;
    const int b0 = blockIdx.x * 32;
    const float* xp = x + (size_t)b0 * NF + n;
    float sk[DDEG];
    #pragma unroll
    for (int k = 0; k < DDEG; ++k) sk[k] = 0.f;
    float mx = 0.f;
    float xv = xp[0];
    float yv = y[b0];
    for (int r = 0; r < 32; ++r) {
      int rn = (r + 1 < 32) ? (r + 1) : r;    // clamped prefetch
      float xnext = xp[(size_t)rn * NF];
      float ynext = y[b0 + rn];
      mx = fmaxf(mx, fabsf(xv));
      float xh = xv * INVX;
      float x2 = xh + xh;
      float Tm = 1.f, Tc = xh;
      sk[0] = fmaf(yv, xh, sk[0]);            // k=1
      #pragma unroll
      for (int k = 2; k <= DDEG; ++k) {
        float Tn = fmaf(x2, Tc, -Tm);
        sk[k - 1] = fmaf(yv, Tn, sk[k - 1]);
        Tm = Tc; Tc = Tn;
      }
      xv = xnext; yv = ynext;
    }
    #pragma unroll
    for (int m = 1; m < 64; m <<= 1) mx = fmaxf(mx, __shfl_xor(mx, m));
    if ((t & 63) == 0)
      atomicMax(reinterpret_cast<unsigned int*>(&wsf[1]), __float_as_uint(mx));
    #pragma unroll
    for (int k = 0; k < DDEG; ++k) atomicAdd(&S[n * DDEG + k], sk[k]);
  } else {
    // ---- coefficient path: thread = (n,h); Chebyshev interp of tanh -------
    const int id = (blockIdx.x - 2048) * 256 + t;   // 0..8191 = n*32+h
    const float a   = W1[id];
    const float b   = b1[id];
    const float w2a = fabsf(W2[id]);
    const float aX  = a * XFIX;
    float cacc[NNODE];
    #pragma unroll
    for (int k = 0; k < NNODE; ++k) cacc[k] = 0.f;
    for (int j = 0; j < NNODE; ++j) {
      float th = (j + 0.5f) * (float)(M_PI / (double)NNODE);
      float tj = __cosf(th);
      float u  = fmaf(aX, tj, b);
      float f  = 1.f - 2.f * frcp(fexp2(K2C * u) + 1.f);   // exact tanh
      float t2 = tj + tj;
      float Tm = 1.f, Tc = tj;
      cacc[0] += f;
      cacc[1] = fmaf(f, tj, cacc[1]);
      #pragma unroll
      for (int k = 2; k < NNODE; ++k) {
        float Tn = fmaf(t2, Tc, -Tm);
        cacc[k] = fmaf(f, Tn, cacc[k]);
        Tm = Tc; Tc = Tn;
      }
    }
    const float sc = 2.0f / (float)NNODE;
    cws[id] = cacc[0] * (1.0f / (float)NNODE);             // c_0
    #pragma unroll
    for (int k = 1; k <= DDEG; ++k) cws[k * 8192 + id] = cacc[k] * sc;
    float tail = 0.f;
    #pragma unroll
    for (int k = DDEG + 1; k < NNODE; ++k) tail += fabsf(cacc[k]) * sc;
    w2eps[id] = w2a * fmaf(3.0f, tail, 3e-3f);             // |W2|*eps
  }
}

// ---------------- combine1: p~ and cert per n --------------------------------
__global__ __launch_bounds__(256) void combine1_kernel(
    const float* __restrict__ W2, const float* __restrict__ b2,
    float* __restrict__ wsf)
{
  const int t = threadIdx.x;
  const int h = t & 31, ng = t >> 5;
  const int n = blockIdx.x * 8 + ng;            // 32 blocks x 8 n
  const int id = n * HID + h;
  const float* S     = wsf + 64;
  const float* cws   = wsf + 7808;
  const float* w2eps = wsf + 245376;
  const float Sy  = wsf[2];
  const float SyA = wsf[3];
  float T = cws[id] * Sy;                       // c_0 * S_0 (S_0 = sum y)
  #pragma unroll
  for (int k = 1; k <= DDEG; ++k)
    T = fmaf(cws[k * 8192 + id], S[n * DDEG + k - 1], T);
  float acc = W2[id] * T;
  float e   = w2eps[id];
  #pragma unroll
  for (int m = 1; m < 32; m <<= 1) {            // reduce over h (32 lanes)
    acc += __shfl_xor(acc, m);
    e   += __shfl_xor(e, m);
  }
  if (h == 0) {
    wsf[7232 + n] = ALPHA_BF - fmaf(b2[n], Sy, acc);   // p~
    wsf[7488 + n] = fmaf(e, SyA, 128.0f);              // cert (+fp slack)
  }
}

// ---------------- combine2: certified flag -----------------------------------
__global__ __launch_bounds__(256) void combine2_kernel(float* __restrict__ wsf)
{
  const int t = threadIdx.x;
  float v = wsf[7232 + t] - wsf[7488 + t];
  int ok = (v >= 0.f) ? 1 : 0;                  // NaN -> 0
  __shared__ int smi[256];
  smi[t] = ok;
  __syncthreads();
  for (int off = 128; off > 0; off >>= 1) {
    if (t < off) smi[t] = smi[t] & smi[t + off];
    __syncthreads();
  }
  if (t == 0) {
    float Xo = __uint_as_float(*reinterpret_cast<unsigned int*>(&wsf[1]));
    wsf[0] = (smi[0] && (Xo <= XFIX)) ? 1.f : 0.f;
  }
}

// ---------------- zero-path output writer ------------------------------------
__global__ __launch_bounds__(256) void zwrite_kernel(const float* __restrict__ wsf,
                                                     float* __restrict__ out)
{
  if (wsf[0] < 0.5f) return;
  int i = blockIdx.x * 256 + threadIdx.x;       // 257 blocks = 65792
  if (i < BATCHN + NF) out[i] = 0.f;
}

// ================= exact fallback path (flagA==0 only) =======================
__global__ __launch_bounds__(256, 2) void zty_kernel(
    const float* __restrict__ x, const float* __restrict__ y,
    const float* __restrict__ W1, const float* __restrict__ b1,
    const float* __restrict__ W2, const float* __restrict__ b2,
    const float* __restrict__ flag, float* __restrict__ part, int rows)
{
  if (flag[0] >= 0.5f) return;
  const int n = threadIdx.x;
  const int blk = blockIdx.x;
  float w1s[HID], b1s[HID], w2[HID];
  float base = b2[n];
  #pragma unroll
  for (int h = 0; h < HID; ++h) {
    w1s[h] = W1[n * HID + h] * K2C;
    b1s[h] = b1[n * HID + h] * K2C;
    w2[h]  = W2[n * HID + h];
    base  += w2[h];
  }
  const int b0 = blk * rows;
  const float* xp = x + (size_t)b0 * NF + n;
  float xv = xp[0];
  float yv = y[b0];
  float zty = 0.f;
  for (int r = 0; r < rows; ++r) {
    int rn = (r + 1 < rows) ? (r + 1) : r;
    float xnext = xp[(size_t)rn * NF];
    float ynext = y[b0 + rn];
    float a0 = 0.f, a1 = 0.f, a2 = 0.f, a3 = 0.f;
    #pragma unroll
    for (int h = 0; h < HID; h += 4) {
      float u0 = fmaf(xv, w1s[h + 0], b1s[h + 0]);
      float u1 = fmaf(xv, w1s[h + 1], b1s[h + 1]);
      float u2 = fmaf(xv, w1s[h + 2], b1s[h + 2]);
      float u3 = fmaf(xv, w1s[h + 3], b1s[h + 3]);
      float e0 = fexp2(u0), e1 = fexp2(u1), e2 = fexp2(u2), e3 = fexp2(u3);
      a0 = fmaf(w2[h + 0], frcp(e0 + 1.f), a0);
      a1 = fmaf(w2[h + 1], frcp(e1 + 1.f), a1);
      a2 = fmaf(w2[h + 2], frcp(e2 + 1.f), a2);
      a3 = fmaf(w2[h + 3], frcp(e3 + 1.f), a3);
    }
    float z = fmaf(-2.f, (a0 + a1) + (a2 + a3), base);
    zty = fmaf(z, yv, zty);
    xv = xnext; yv = ynext;
  }
  part[(size_t)blk * NF + n] = zty;
}

__global__ __launch_bounds__(256) void reduce1(const float* __restrict__ flag,
                                               const float* __restrict__ part,
                                               float* __restrict__ part2,
                                               int chunks)
{
  if (flag[0] >= 0.5f) return;
  int n = threadIdx.x, j = blockIdx.x;
  float s = 0.f;
  for (int k = 0; k < chunks; ++k) s += part[(size_t)(j * chunks + k) * NF + n];
  part2[(size_t)j * NF + n] = s;
}

__global__ __launch_bounds__(256) void reduce2(const float* __restrict__ flag,
                                               const float* __restrict__ part2,
                                               float* __restrict__ p)
{
  if (flag[0] >= 0.5f) return;
  int n = threadIdx.x;
  float s = 0.f;
  for (int k = 0; k < 64; ++k) s += part2[(size_t)k * NF + n];
  p[n] = ALPHA_BF - s;
}

__global__ __launch_bounds__(256) void qinit(const float* __restrict__ flag,
                                             float* __restrict__ Q)
{
  if (flag[0] >= 0.5f) return;
  int idx = blockIdx.x * 256 + threadIdx.x;
  int i = idx >> 8, j = idx & 255;
  Q[idx] = (i == j) ? JITTERF : 0.f;
}

__global__ __launch_bounds__(256) void qacc(
    const float* __restrict__ x,
    const float* __restrict__ W1, const float* __restrict__ b1,
    const float* __restrict__ W2, const float* __restrict__ b2,
    const float* __restrict__ flag, float* __restrict__ Q)
{
  if (flag[0] >= 0.5f) return;
  __shared__ float zsh[64 * NF];                // 64 KiB
  const int t = threadIdx.x;
  float w1s[HID], b1s[HID], w2[HID];
  float base = b2[t];
  #pragma unroll
  for (int h = 0; h < HID; ++h) {
    w1s[h] = W1[t * HID + h] * K2C;
    b1s[h] = b1[t * HID + h] * K2C;
    w2[h]  = W2[t * HID + h];
    base  += w2[h];
  }
  const int b0 = blockIdx.x * 64;
  for (int r = 0; r < 64; ++r) {
    float xv = x[(size_t)(b0 + r) * NF + t];
    float acc = 0.f;
    #pragma unroll
    for (int h = 0; h < HID; ++h) {
      float u = fmaf(xv, w1s[h], b1s[h]);
      acc = fmaf(w2[h], frcp(fexp2(u) + 1.f), acc);
    }
    zsh[r * NF + t] = fmaf(-2.f, acc, base);
  }
  __syncthreads();
  for (int j = 0; j < NF; ++j) {
    float s = 0.f;
    for (int r = 0; r < 64; ++r) s += zsh[r * NF + t] * zsh[r * NF + j];
    atomicAdd(&Q[t * NF + j], s);
  }
}

__global__ __launch_bounds__(256) void solver_kernel(
    const float* __restrict__ flag, const float* __restrict__ p,
    const float* __restrict__ Q, float* __restrict__ L, float* __restrict__ Qe,
    float* __restrict__ lamg, float* __restrict__ dout_lam)
{
  if (flag[0] >= 0.5f) return;
  const int t = threadIdx.x;
  __shared__ float sm[NF];
  __shared__ float lam_s[NF];
  for (int i = 0; i < NF; ++i) L[i * NF + t] = (t <= i) ? Q[i * NF + t] : 0.f;
  __syncthreads();
  for (int k = 0; k < NF; ++k) {                // right-looking Cholesky
    if (t == 0) L[k * NF + k] = sqrtf(L[k * NF + k]);
    __syncthreads();
    float lkk = L[k * NF + k];
    if (t > k) L[t * NF + k] /= lkk;
    __syncthreads();
    if (t > k) {
      float ltk = L[t * NF + k];
      for (int i = k + 1; i <= t; ++i) L[t * NF + i] -= ltk * L[i * NF + k];
    }
    __syncthreads();
  }
  for (int i = 0; i < NF; ++i) {                // Qe = L L^T
    int m = (i < t) ? i : t;
    float s = 0.f;
    for (int k = 0; k <= m; ++k) s += L[i * NF + k] * L[t * NF + k];
    Qe[i * NF + t] = s;
  }
  __syncthreads();
  lam_s[t] = 1.f;
  __syncthreads();
  float lmax = 1.f;
  for (int it = 0; it < 256; ++it) {            // power iteration
    float s = 0.f;
    for (int k = 0; k < NF; ++k) s += Qe[t * NF + k] * lam_s[k];
    sm[t] = s * s;
    __syncthreads();
    for (int off = 128; off > 0; off >>= 1) {
      if (t < off) sm[t] += sm[t + off];
      __syncthreads();
    }
    float nrm = sqrtf(sm[0]);
    __syncthreads();
    lam_s[t] = s / nrm;
    lmax = nrm;
    __syncthreads();
  }
  float step = 1.0f / lmax;
  lam_s[t] = 0.f;
  __syncthreads();
  float pv = p[t];
  for (int it = 0; it < QP_ITERS_N; ++it) {
    float s = 0.f;
    for (int k = 0; k < NF; ++k) s += Qe[t * NF + k] * lam_s[k];
    float ln = fmaxf(lam_s[t] - step * (s + pv), 0.f);
    __syncthreads();
    lam_s[t] = ln;
    __syncthreads();
  }
  dout_lam[t] = lam_s[t];
  lamg[t] = lam_s[t];
}

__global__ __launch_bounds__(256) void yhat_kernel(
    const float* __restrict__ x,
    const float* __restrict__ W1, const float* __restrict__ b1,
    const float* __restrict__ W2, const float* __restrict__ b2,
    const float* __restrict__ flag, const float* __restrict__ lamg,
    float* __restrict__ yhat)
{
  if (flag[0] >= 0.5f) return;
  const int b = blockIdx.x * 256 + threadIdx.x;
  __shared__ float lam_s[NF];
  lam_s[threadIdx.x] = lamg[threadIdx.x];
  __syncthreads();
  float acc = 0.f;
  for (int n = 0; n < NF; ++n) {
    float xv = x[(size_t)b * NF + n];
    float zacc = 0.f, base = b2[n];
    for (int h = 0; h < HID; ++h) {
      float w2h = W2[n * HID + h];
      base += w2h;
      float u = fmaf(xv, W1[n * HID + h] * K2C, b1[n * HID + h] * K2C);
      zacc = fmaf(w2h, frcp(fexp2(u) + 1.f), zacc);
    }
    acc = fmaf(fmaf(-2.f, zacc, base), lam_s[n], acc);
  }
  yhat[b] = acc;
}

// ---------------- host launcher ---------------------------------------------
extern "C" void kernel_launch(void* const* d_in, const int* in_sizes, int n_in,
                              void* d_out, int out_size, void* d_ws, size_t ws_size,
                              hipStream_t stream) {
  const float* x  = (const float*)d_in[0];
  const float* y  = (const float*)d_in[1];
  const float* W1 = (const float*)d_in[2];
  const float* b1 = (const float*)d_in[3];
  const float* W2 = (const float*)d_in[4];
  const float* b2 = (const float*)d_in[5];
  float* out = (float*)d_out;            // [0,65536): y_hat ; [65536,65792): lam
  float* ws  = (float*)d_ws;

  // fallback grid sizing by workspace (deterministic)
  int nblk = 2048;
  size_t need = (7808 + (size_t)nblk * NF + 16384 + 256 + 256 + 3 * 65536) * 4;
  if (ws_size < need) nblk = 1024;
  const int rows = BATCHN / nblk;
  const int chunks = nblk / 64;

  float* flagA  = ws;                    // ws[0]
  float* part   = ws + 7808;
  float* part2  = part + (size_t)nblk * NF;
  float* p_ex   = part2 + 16384;
  float* lam    = p_ex + 256;
  float* Q      = lam + 256;
  float* L      = Q + 65536;
  float* Qe     = L + 65536;

  // fast certified path
  zero_kernel<<<29, 256, 0, stream>>>(ws);
  ysum_kernel<<<64, 256, 0, stream>>>(y, ws);
  momentcoeff_kernel<<<2080, 256, 0, stream>>>(x, y, W1, b1, W2, ws);
  combine1_kernel<<<32, 256, 0, stream>>>(W2, b2, ws);
  combine2_kernel<<<1, 256, 0, stream>>>(ws);
  zwrite_kernel<<<257, 256, 0, stream>>>(ws, out);

  // exact fallback (flag-guarded; near-free when certified)
  zty_kernel<<<nblk, 256, 0, stream>>>(x, y, W1, b1, W2, b2, flagA, part, rows);
  reduce1<<<64, 256, 0, stream>>>(flagA, part, part2, chunks);
  reduce2<<<1, 256, 0, stream>>>(flagA, part2, p_ex);
  qinit<<<256, 256, 0, stream>>>(flagA, Q);
  qacc<<<1024, 256, 0, stream>>>(x, W1, b1, W2, b2, flagA, Q);
  solver_kernel<<<1, 256, 0, stream>>>(flagA, p_ex, Q, L, Qe, lam, out + BATCHN);
  yhat_kernel<<<BATCHN / 256, 256, 0, stream>>>(x, W1, b1, W2, b2, flagA, lam, out);
}

// Round 6
// 190.367 us; speedup vs baseline: 4.6984x; 4.6984x over previous
//
#include <hip/hip_runtime.h>
#include <math.h>

// DifferentiableLassoSelector: B=65536, n=256, h=32.
// p = 6553.6 - Z^T y > 0 elementwise (~40 sigma margin) => projected-gradient
// QP stays at lam=0 exactly => y_hat = 0 exactly.
// Fast path: Chebyshev-moment factorization. tanh(W1[n,h]*x+b1[n,h]) expanded
// in T_k(x/X) (X=6.5, 28 terms); Z^T y then needs only h-independent moments
// S_k[n] = sum_b y_b T_k(x[b,n]/X). Moments are accumulated via per-block
// partials + a deterministic tree reduce (NO global atomicAdd — r4 showed
// 14.7M atomics to 7168 addresses serialize to 891us / 2.5% VALUBusy).
// Device-side certification: per-(n,h) truncation error from observed coeff
// tail; zero path taken only if min_n(p~ - cert) >= 0 AND max|x| <= X.
// Otherwise the exact exp2-tanh fallback pipeline (flag-guarded stubs) runs.

#define NF 256
#define HID 32
#define BATCHN 65536
#define ALPHA_BF 6553.6f               // ALPHA * BATCH
#define JITTERF 1e-4f
#define QP_ITERS_N 500
#define K2C 2.8853900817779268f        // 2*log2(e): exp2(K2C*u) = e^{2u}
#define XFIX 6.5f
#define INVX (1.0f / 6.5f)
#define DDEG 28                        // poly degree (c_0..c_28)
#define NNODE 44                       // Chebyshev interpolation nodes

// ws float layout:
// 0: flagA | 1: Xobs(uint bits) | 8..72: ypart[64] | 72..136: yabspart[64]
// 256:     S[7168]              -> 7424
// 7424:    ptil[256]            -> 7680
// 7680:    cert[256]            -> 7936
// 8192:    c[29][8192]          -> 245760
// 245760:  w2eps[8192]          -> 253952
// 253952:  pmom[nblkm][7168]  OVERLAID WITH  fallback buffers
//          (pmom is dead before flagA is decided; fallback only runs flagA==0)

#if __has_builtin(__builtin_amdgcn_exp2f)
__device__ __forceinline__ float fexp2(float x) { return __builtin_amdgcn_exp2f(x); }
#else
__device__ __forceinline__ float fexp2(float x) { return exp2f(x); }
#endif
#if __has_builtin(__builtin_amdgcn_rcpf)
__device__ __forceinline__ float frcp(float x) { return __builtin_amdgcn_rcpf(x); }
#else
__device__ __forceinline__ float frcp(float x) { return 1.0f / x; }
#endif

// ---------------- zero scratch header (flag, Xobs, y partial slots) ----------
__global__ __launch_bounds__(256) void zero_kernel(float* __restrict__ wsf)
{
  wsf[threadIdx.x] = 0.f;               // one block covers header [0,256)
}

// ---------------- y partial sums (per-block, atomic-free) --------------------
__global__ __launch_bounds__(256) void ysum_kernel(const float* __restrict__ y,
                                                   float* __restrict__ wsf)
{
  int t = threadIdx.x;
  int i = (blockIdx.x * 256 + t) * 4;         // 64 blocks x 256 x 4 = 65536
  float4 v = *reinterpret_cast<const float4*>(y + i);
  float s  = (v.x + v.y) + (v.z + v.w);
  float sa = (fabsf(v.x) + fabsf(v.y)) + (fabsf(v.z) + fabsf(v.w));
  #pragma unroll
  for (int m = 1; m < 64; m <<= 1) {
    s  += __shfl_xor(s, m);
    sa += __shfl_xor(sa, m);
  }
  __shared__ float ls[4], la[4];
  int w = t >> 6;
  if ((t & 63) == 0) { ls[w] = s; la[w] = sa; }
  __syncthreads();
  if (t == 0) {
    wsf[8  + blockIdx.x] = (ls[0] + ls[1]) + (ls[2] + ls[3]);
    wsf[72 + blockIdx.x] = (la[0] + la[1]) + (la[2] + la[3]);
  }
}

// ---------------- fused moment partials (blocks < nblkm) + coeffs ------------
__global__ __launch_bounds__(256, 4) void momentcoeff_kernel(
    const float* __restrict__ x, const float* __restrict__ y,
    const float* __restrict__ W1, const float* __restrict__ b1,
    const float* __restrict__ W2, float* __restrict__ wsf,
    int nblkm, int rows)
{
  const int t = threadIdx.x;
  float* cws   = wsf + 8192;
  float* w2eps = wsf + 245760;
  float* pmom  = wsf + 253952;

  if (blockIdx.x < nblkm) {
    // ---- moment path: thread = feature n; `rows` rows per block ----
    const int n = t;
    const int b0 = blockIdx.x * rows;
    const float* xp = x + (size_t)b0 * NF + n;
    float sk[DDEG];
    #pragma unroll
    for (int k = 0; k < DDEG; ++k) sk[k] = 0.f;
    float mx = 0.f;
    float xv = xp[0];
    float yv = y[b0];
    for (int r = 0; r < rows; ++r) {
      int rn = (r + 1 < rows) ? (r + 1) : r;    // clamped prefetch
      float xnext = xp[(size_t)rn * NF];
      float ynext = y[b0 + rn];
      mx = fmaxf(mx, fabsf(xv));
      float xh = xv * INVX;
      float x2 = xh + xh;
      float Tm = 1.f, Tc = xh;
      sk[0] = fmaf(yv, xh, sk[0]);              // k=1
      #pragma unroll
      for (int k = 2; k <= DDEG; ++k) {
        float Tn = fmaf(x2, Tc, -Tm);
        sk[k - 1] = fmaf(yv, Tn, sk[k - 1]);
        Tm = Tc; Tc = Tn;
      }
      xv = xnext; yv = ynext;
    }
    #pragma unroll
    for (int m = 1; m < 64; m <<= 1) mx = fmaxf(mx, __shfl_xor(mx, m));
    if ((t & 63) == 0)
      atomicMax(reinterpret_cast<unsigned int*>(&wsf[1]), __float_as_uint(mx));
    // plain vector stores: n*28 floats = n*112 B, 16B-aligned (112 = 7*16)
    float* dst = pmom + (size_t)blockIdx.x * 7168 + n * DDEG;
    #pragma unroll
    for (int q = 0; q < 7; ++q)
      *reinterpret_cast<float4*>(dst + q * 4) =
          make_float4(sk[q * 4], sk[q * 4 + 1], sk[q * 4 + 2], sk[q * 4 + 3]);
  } else {
    // ---- coefficient path: thread = (n,h); Chebyshev interp of tanh -------
    const int id = (blockIdx.x - nblkm) * 256 + t;   // 0..8191 = n*32+h
    const float a   = W1[id];
    const float b   = b1[id];
    const float w2a = fabsf(W2[id]);
    const float aX  = a * XFIX;
    float cacc[NNODE];
    #pragma unroll
    for (int k = 0; k < NNODE; ++k) cacc[k] = 0.f;
    for (int j = 0; j < NNODE; ++j) {
      float th = (j + 0.5f) * (float)(M_PI / (double)NNODE);
      float tj = __cosf(th);
      float u  = fmaf(aX, tj, b);
      float f  = 1.f - 2.f * frcp(fexp2(K2C * u) + 1.f);   // exact tanh
      float t2 = tj + tj;
      float Tm = 1.f, Tc = tj;
      cacc[0] += f;
      cacc[1] = fmaf(f, tj, cacc[1]);
      #pragma unroll
      for (int k = 2; k < NNODE; ++k) {
        float Tn = fmaf(t2, Tc, -Tm);
        cacc[k] = fmaf(f, Tn, cacc[k]);
        Tm = Tc; Tc = Tn;
      }
    }
    const float sc = 2.0f / (float)NNODE;
    cws[id] = cacc[0] * (1.0f / (float)NNODE);             // c_0
    #pragma unroll
    for (int k = 1; k <= DDEG; ++k) cws[k * 8192 + id] = cacc[k] * sc;
    float tail = 0.f;
    #pragma unroll
    for (int k = DDEG + 1; k < NNODE; ++k) tail += fabsf(cacc[k]) * sc;
    w2eps[id] = w2a * fmaf(3.0f, tail, 3e-3f);             // |W2|*eps
  }
}

// ---------------- deterministic moment reduce: S[t] = sum_j pmom[j][t] -------
__global__ __launch_bounds__(256) void mreduce_kernel(float* __restrict__ wsf,
                                                      int nblkm)
{
  const int t = blockIdx.x * 256 + threadIdx.x;   // 28 blocks -> 7168
  const float* p = wsf + 253952 + t;
  float s0 = 0.f, s1 = 0.f, s2 = 0.f, s3 = 0.f;
  for (int j = 0; j < nblkm; j += 4) {            // nblkm is a multiple of 4
    s0 += p[(size_t)j * 7168];
    s1 += p[(size_t)(j + 1) * 7168];
    s2 += p[(size_t)(j + 2) * 7168];
    s3 += p[(size_t)(j + 3) * 7168];
  }
  wsf[256 + t] = (s0 + s1) + (s2 + s3);
}

// ---------------- combine1: p~ and cert per n --------------------------------
__global__ __launch_bounds__(256) void combine1_kernel(
    const float* __restrict__ W2, const float* __restrict__ b2,
    float* __restrict__ wsf)
{
  const int t = threadIdx.x;
  __shared__ float shv[2];
  if (t < 64) {                                  // block-local Sy reduction
    float a = wsf[8 + t], bb = wsf[72 + t];
    #pragma unroll
    for (int m = 1; m < 64; m <<= 1) {
      a  += __shfl_xor(a, m);
      bb += __shfl_xor(bb, m);
    }
    if (t == 0) { shv[0] = a; shv[1] = bb; }
  }
  __syncthreads();
  const float Sy  = shv[0];
  const float SyA = shv[1];
  const int h = t & 31, ng = t >> 5;
  const int n = blockIdx.x * 8 + ng;             // 32 blocks x 8 n
  const int id = n * HID + h;
  const float* S     = wsf + 256;
  const float* cws   = wsf + 8192;
  const float* w2eps = wsf + 245760;
  float T = cws[id] * Sy;                        // c_0 * S_0 (S_0 = sum y)
  #pragma unroll
  for (int k = 1; k <= DDEG; ++k)
    T = fmaf(cws[k * 8192 + id], S[n * DDEG + k - 1], T);
  float acc = W2[id] * T;
  float e   = w2eps[id];
  #pragma unroll
  for (int m = 1; m < 32; m <<= 1) {             // reduce over h (32 lanes)
    acc += __shfl_xor(acc, m);
    e   += __shfl_xor(e, m);
  }
  if (h == 0) {
    wsf[7424 + n] = ALPHA_BF - fmaf(b2[n], Sy, acc);   // p~
    wsf[7680 + n] = fmaf(e, SyA, 128.0f);              // cert (+fp slack)
  }
}

// ---------------- combine2: certified flag -----------------------------------
__global__ __launch_bounds__(256) void combine2_kernel(float* __restrict__ wsf)
{
  const int t = threadIdx.x;
  float v = wsf[7424 + t] - wsf[7680 + t];
  int ok = (v >= 0.f) ? 1 : 0;                   // NaN -> 0
  __shared__ int smi[256];
  smi[t] = ok;
  __syncthreads();
  for (int off = 128; off > 0; off >>= 1) {
    if (t < off) smi[t] = smi[t] & smi[t + off];
    __syncthreads();
  }
  if (t == 0) {
    float Xo = __uint_as_float(*reinterpret_cast<unsigned int*>(&wsf[1]));
    wsf[0] = (smi[0] && (Xo <= XFIX)) ? 1.f : 0.f;
  }
}

// ---------------- zero-path output writer ------------------------------------
__global__ __launch_bounds__(256) void zwrite_kernel(const float* __restrict__ wsf,
                                                     float* __restrict__ out)
{
  if (wsf[0] < 0.5f) return;
  int i = blockIdx.x * 256 + threadIdx.x;        // 257 blocks = 65792
  if (i < BATCHN + NF) out[i] = 0.f;
}

// ================= exact fallback path (flagA==0 only) =======================
__global__ __launch_bounds__(256, 2) void zty_kernel(
    const float* __restrict__ x, const float* __restrict__ y,
    const float* __restrict__ W1, const float* __restrict__ b1,
    const float* __restrict__ W2, const float* __restrict__ b2,
    const float* __restrict__ flag, float* __restrict__ part, int rows)
{
  if (flag[0] >= 0.5f) return;
  const int n = threadIdx.x;
  const int blk = blockIdx.x;
  float w1s[HID], b1s[HID], w2[HID];
  float base = b2[n];
  #pragma unroll
  for (int h = 0; h < HID; ++h) {
    w1s[h] = W1[n * HID + h] * K2C;
    b1s[h] = b1[n * HID + h] * K2C;
    w2[h]  = W2[n * HID + h];
    base  += w2[h];
  }
  const int b0 = blk * rows;
  const float* xp = x + (size_t)b0 * NF + n;
  float xv = xp[0];
  float yv = y[b0];
  float zty = 0.f;
  for (int r = 0; r < rows; ++r) {
    int rn = (r + 1 < rows) ? (r + 1) : r;
    float xnext = xp[(size_t)rn * NF];
    float ynext = y[b0 + rn];
    float a0 = 0.f, a1 = 0.f, a2 = 0.f, a3 = 0.f;
    #pragma unroll
    for (int h = 0; h < HID; h += 4) {
      float u0 = fmaf(xv, w1s[h + 0], b1s[h + 0]);
      float u1 = fmaf(xv, w1s[h + 1], b1s[h + 1]);
      float u2 = fmaf(xv, w1s[h + 2], b1s[h + 2]);
      float u3 = fmaf(xv, w1s[h + 3], b1s[h + 3]);
      float e0 = fexp2(u0), e1 = fexp2(u1), e2 = fexp2(u2), e3 = fexp2(u3);
      a0 = fmaf(w2[h + 0], frcp(e0 + 1.f), a0);
      a1 = fmaf(w2[h + 1], frcp(e1 + 1.f), a1);
      a2 = fmaf(w2[h + 2], frcp(e2 + 1.f), a2);
      a3 = fmaf(w2[h + 3], frcp(e3 + 1.f), a3);
    }
    float z = fmaf(-2.f, (a0 + a1) + (a2 + a3), base);
    zty = fmaf(z, yv, zty);
    xv = xnext; yv = ynext;
  }
  part[(size_t)blk * NF + n] = zty;
}

__global__ __launch_bounds__(256) void reduce1(const float* __restrict__ flag,
                                               const float* __restrict__ part,
                                               float* __restrict__ part2,
                                               int chunks)
{
  if (flag[0] >= 0.5f) return;
  int n = threadIdx.x, j = blockIdx.x;
  float s = 0.f;
  for (int k = 0; k < chunks; ++k) s += part[(size_t)(j * chunks + k) * NF + n];
  part2[(size_t)j * NF + n] = s;
}

__global__ __launch_bounds__(256) void reduce2(const float* __restrict__ flag,
                                               const float* __restrict__ part2,
                                               float* __restrict__ p)
{
  if (flag[0] >= 0.5f) return;
  int n = threadIdx.x;
  float s = 0.f;
  for (int k = 0; k < 64; ++k) s += part2[(size_t)k * NF + n];
  p[n] = ALPHA_BF - s;
}

__global__ __launch_bounds__(256) void qinit(const float* __restrict__ flag,
                                             float* __restrict__ Q)
{
  if (flag[0] >= 0.5f) return;
  int idx = blockIdx.x * 256 + threadIdx.x;
  int i = idx >> 8, j = idx & 255;
  Q[idx] = (i == j) ? JITTERF : 0.f;
}

__global__ __launch_bounds__(256) void qacc(
    const float* __restrict__ x,
    const float* __restrict__ W1, const float* __restrict__ b1,
    const float* __restrict__ W2, const float* __restrict__ b2,
    const float* __restrict__ flag, float* __restrict__ Q)
{
  if (flag[0] >= 0.5f) return;
  __shared__ float zsh[64 * NF];                 // 64 KiB
  const int t = threadIdx.x;
  float w1s[HID], b1s[HID], w2[HID];
  float base = b2[t];
  #pragma unroll
  for (int h = 0; h < HID; ++h) {
    w1s[h] = W1[t * HID + h] * K2C;
    b1s[h] = b1[t * HID + h] * K2C;
    w2[h]  = W2[t * HID + h];
    base  += w2[h];
  }
  const int b0 = blockIdx.x * 64;
  for (int r = 0; r < 64; ++r) {
    float xv = x[(size_t)(b0 + r) * NF + t];
    float acc = 0.f;
    #pragma unroll
    for (int h = 0; h < HID; ++h) {
      float u = fmaf(xv, w1s[h], b1s[h]);
      acc = fmaf(w2[h], frcp(fexp2(u) + 1.f), acc);
    }
    zsh[r * NF + t] = fmaf(-2.f, acc, base);
  }
  __syncthreads();
  for (int j = 0; j < NF; ++j) {
    float s = 0.f;
    for (int r = 0; r < 64; ++r) s += zsh[r * NF + t] * zsh[r * NF + j];
    atomicAdd(&Q[t * NF + j], s);
  }
}

__global__ __launch_bounds__(256) void solver_kernel(
    const float* __restrict__ flag, const float* __restrict__ p,
    const float* __restrict__ Q, float* __restrict__ L, float* __restrict__ Qe,
    float* __restrict__ lamg, float* __restrict__ dout_lam)
{
  if (flag[0] >= 0.5f) return;
  const int t = threadIdx.x;
  __shared__ float sm[NF];
  __shared__ float lam_s[NF];
  for (int i = 0; i < NF; ++i) L[i * NF + t] = (t <= i) ? Q[i * NF + t] : 0.f;
  __syncthreads();
  for (int k = 0; k < NF; ++k) {                 // right-looking Cholesky
    if (t == 0) L[k * NF + k] = sqrtf(L[k * NF + k]);
    __syncthreads();
    float lkk = L[k * NF + k];
    if (t > k) L[t * NF + k] /= lkk;
    __syncthreads();
    if (t > k) {
      float ltk = L[t * NF + k];
      for (int i = k + 1; i <= t; ++i) L[t * NF + i] -= ltk * L[i * NF + k];
    }
    __syncthreads();
  }
  for (int i = 0; i < NF; ++i) {                 // Qe = L L^T
    int m = (i < t) ? i : t;
    float s = 0.f;
    for (int k = 0; k <= m; ++k) s += L[i * NF + k] * L[t * NF + k];
    Qe[i * NF + t] = s;
  }
  __syncthreads();
  lam_s[t] = 1.f;
  __syncthreads();
  float lmax = 1.f;
  for (int it = 0; it < 256; ++it) {             // power iteration
    float s = 0.f;
    for (int k = 0; k < NF; ++k) s += Qe[t * NF + k] * lam_s[k];
    sm[t] = s * s;
    __syncthreads();
    for (int off = 128; off > 0; off >>= 1) {
      if (t < off) sm[t] += sm[t + off];
      __syncthreads();
    }
    float nrm = sqrtf(sm[0]);
    __syncthreads();
    lam_s[t] = s / nrm;
    lmax = nrm;
    __syncthreads();
  }
  float step = 1.0f / lmax;
  lam_s[t] = 0.f;
  __syncthreads();
  float pv = p[t];
  for (int it = 0; it < QP_ITERS_N; ++it) {
    float s = 0.f;
    for (int k = 0; k < NF; ++k) s += Qe[t * NF + k] * lam_s[k];
    float ln = fmaxf(lam_s[t] - step * (s + pv), 0.f);
    __syncthreads();
    lam_s[t] = ln;
    __syncthreads();
  }
  dout_lam[t] = lam_s[t];
  lamg[t] = lam_s[t];
}

__global__ __launch_bounds__(256) void yhat_kernel(
    const float* __restrict__ x,
    const float* __restrict__ W1, const float* __restrict__ b1,
    const float* __restrict__ W2, const float* __restrict__ b2,
    const float* __restrict__ flag, const float* __restrict__ lamg,
    float* __restrict__ yhat)
{
  if (flag[0] >= 0.5f) return;
  const int b = blockIdx.x * 256 + threadIdx.x;
  __shared__ float lam_s[NF];
  lam_s[threadIdx.x] = lamg[threadIdx.x];
  __syncthreads();
  float acc = 0.f;
  for (int n = 0; n < NF; ++n) {
    float xv = x[(size_t)b * NF + n];
    float zacc = 0.f, base = b2[n];
    for (int h = 0; h < HID; ++h) {
      float w2h = W2[n * HID + h];
      base += w2h;
      float u = fmaf(xv, W1[n * HID + h] * K2C, b1[n * HID + h] * K2C);
      zacc = fmaf(w2h, frcp(fexp2(u) + 1.f), zacc);
    }
    acc = fmaf(fmaf(-2.f, zacc, base), lam_s[n], acc);
  }
  yhat[b] = acc;
}

// ---------------- host launcher ---------------------------------------------
extern "C" void kernel_launch(void* const* d_in, const int* in_sizes, int n_in,
                              void* d_out, int out_size, void* d_ws, size_t ws_size,
                              hipStream_t stream) {
  const float* x  = (const float*)d_in[0];
  const float* y  = (const float*)d_in[1];
  const float* W1 = (const float*)d_in[2];
  const float* b1 = (const float*)d_in[3];
  const float* W2 = (const float*)d_in[4];
  const float* b2 = (const float*)d_in[5];
  float* out = (float*)d_out;            // [0,65536): y_hat ; [65536,65792): lam
  float* ws  = (float*)d_ws;

  // size tiers (deterministic in ws_size): pmom overlays fallback buffers
  int nblkm = 1024, nblk = 2048;
  auto fb_floats = [](int bk) -> size_t {
    return (size_t)bk * NF + 16384 + 256 + 256 + 3 * 65536;
  };
  auto fits = [&](int bm, int bk) -> bool {
    size_t pm = (size_t)bm * 7168;
    size_t fb = fb_floats(bk);
    size_t tot = 253952 + (pm > fb ? pm : fb);
    return tot * 4 <= ws_size;
  };
  while (nblkm > 64 && !fits(nblkm, nblk)) nblkm >>= 1;
  if (!fits(nblkm, nblk)) nblk = 1024;
  const int rows_m = BATCHN / nblkm;
  const int rows_f = BATCHN / nblk;
  const int chunks = nblk / 64;

  float* flagA  = ws;                    // ws[0]
  float* ovl    = ws + 253952;           // pmom / fallback overlay
  float* part   = ovl;
  float* part2  = part + (size_t)nblk * NF;
  float* p_ex   = part2 + 16384;
  float* lam    = p_ex + 256;
  float* Q      = lam + 256;
  float* L      = Q + 65536;
  float* Qe     = L + 65536;

  // fast certified path (atomic-free except order-exact atomicMax on |x|)
  zero_kernel<<<1, 256, 0, stream>>>(ws);
  ysum_kernel<<<64, 256, 0, stream>>>(y, ws);
  momentcoeff_kernel<<<nblkm + 32, 256, 0, stream>>>(x, y, W1, b1, W2, ws,
                                                     nblkm, rows_m);
  mreduce_kernel<<<28, 256, 0, stream>>>(ws, nblkm);
  combine1_kernel<<<32, 256, 0, stream>>>(W2, b2, ws);
  combine2_kernel<<<1, 256, 0, stream>>>(ws);
  zwrite_kernel<<<257, 256, 0, stream>>>(ws, out);

  // exact fallback (flag-guarded; near-free when certified)
  zty_kernel<<<nblk, 256, 0, stream>>>(x, y, W1, b1, W2, b2, flagA, part, rows_f);
  reduce1<<<64, 256, 0, stream>>>(flagA, part, part2, chunks);
  reduce2<<<1, 256, 0, stream>>>(flagA, part2, p_ex);
  qinit<<<256, 256, 0, stream>>>(flagA, Q);
  qacc<<<1024, 256, 0, stream>>>(x, W1, b1, W2, b2, flagA, Q);
  solver_kernel<<<1, 256, 0, stream>>>(flagA, p_ex, Q, L, Qe, lam, out + BATCHN);
  yhat_kernel<<<BATCHN / 256, 256, 0, stream>>>(x, W1, b1, W2, b2, flagA, lam, out);
}

// Round 7
// 102.278 us; speedup vs baseline: 8.7450x; 1.8613x over previous
//
#include <hip/hip_runtime.h>
#include <math.h>

// DifferentiableLassoSelector: B=65536, n=256, h=32.
// p = 6553.6 - Z^T y > 0 elementwise (~40 sigma margin) => projected-gradient
// QP stays at lam=0 exactly => y_hat = 0 exactly.
// Fast path: Chebyshev-moment factorization. tanh(W1[n,h]*x+b1[n,h]) expanded
// in T_k(x/X) (X=6.5, 28 terms); Z^T y then needs only h-independent moments
// S_k[n] = sum_b y_b T_k(x[b,n]/X). r4: global atomics serialize (891us).
// r6: 28-block reduce is latency-bound (87.7us @1.2% occupancy) and the
// moment kernel's serial recurrence leaves VALU 77% idle. This round:
// ILP-4 moment kernel (4 independent row-recurrences + prefetch) and a
// 2-stage 448-block reduce (in-place, race-free).
// Device-side certification: per-(n,h) truncation error from observed coeff
// tail; zero path taken only if min_n(p~ - cert) >= 0 AND max|x| <= X.
// Otherwise the exact exp2-tanh fallback pipeline (flag-guarded stubs) runs.

#define NF 256
#define HID 32
#define BATCHN 65536
#define ALPHA_BF 6553.6f               // ALPHA * BATCH
#define JITTERF 1e-4f
#define QP_ITERS_N 500
#define K2C 2.8853900817779268f        // 2*log2(e): exp2(K2C*u) = e^{2u}
#define XFIX 6.5f
#define INVX (1.0f / 6.5f)
#define DDEG 28                        // poly degree (c_0..c_28)
#define NNODE 44                       // Chebyshev interpolation nodes

// ws float layout:
// 0: flagA | 1: Xobs(uint bits) | 8..72: ypart[64] | 72..136: yabspart[64]
// 256:     S[7168]              -> 7424
// 7424:    ptil[256]            -> 7680
// 7680:    cert[256]            -> 7936
// 8192:    c[29][8192]          -> 245760
// 245760:  w2eps[8192]          -> 253952
// 253952:  pmom[nblkm][7168]  OVERLAID WITH  fallback buffers
//          (pmom is dead before flagA is decided; fallback only runs flagA==0)

#if __has_builtin(__builtin_amdgcn_exp2f)
__device__ __forceinline__ float fexp2(float x) { return __builtin_amdgcn_exp2f(x); }
#else
__device__ __forceinline__ float fexp2(float x) { return exp2f(x); }
#endif
#if __has_builtin(__builtin_amdgcn_rcpf)
__device__ __forceinline__ float frcp(float x) { return __builtin_amdgcn_rcpf(x); }
#else
__device__ __forceinline__ float frcp(float x) { return 1.0f / x; }
#endif

// ---------------- zero scratch header (flag, Xobs, y partial slots) ----------
__global__ __launch_bounds__(256) void zero_kernel(float* __restrict__ wsf)
{
  wsf[threadIdx.x] = 0.f;               // one block covers header [0,256)
}

// ---------------- y partial sums (per-block, atomic-free) --------------------
__global__ __launch_bounds__(256) void ysum_kernel(const float* __restrict__ y,
                                                   float* __restrict__ wsf)
{
  int t = threadIdx.x;
  int i = (blockIdx.x * 256 + t) * 4;         // 64 blocks x 256 x 4 = 65536
  float4 v = *reinterpret_cast<const float4*>(y + i);
  float s  = (v.x + v.y) + (v.z + v.w);
  float sa = (fabsf(v.x) + fabsf(v.y)) + (fabsf(v.z) + fabsf(v.w));
  #pragma unroll
  for (int m = 1; m < 64; m <<= 1) {
    s  += __shfl_xor(s, m);
    sa += __shfl_xor(sa, m);
  }
  __shared__ float ls[4], la[4];
  int w = t >> 6;
  if ((t & 63) == 0) { ls[w] = s; la[w] = sa; }
  __syncthreads();
  if (t == 0) {
    wsf[8  + blockIdx.x] = (ls[0] + ls[1]) + (ls[2] + ls[3]);
    wsf[72 + blockIdx.x] = (la[0] + la[1]) + (la[2] + la[3]);
  }
}

// ---------------- fused moment partials (blocks < nblkm) + coeffs ------------
__global__ __launch_bounds__(256, 4) void momentcoeff_kernel(
    const float* __restrict__ x, const float* __restrict__ y,
    const float* __restrict__ W1, const float* __restrict__ b1,
    const float* __restrict__ W2, float* __restrict__ wsf,
    int nblkm, int rows)
{
  const int t = threadIdx.x;
  float* cws   = wsf + 8192;
  float* w2eps = wsf + 245760;
  float* pmom  = wsf + 253952;

  if (blockIdx.x < nblkm) {
    // ---- moment path: thread = feature n; ILP-4 over rows ----
    const int n = t;
    const int b0 = blockIdx.x * rows;
    const float* xp = x + (size_t)b0 * NF + n;
    const float* yp = y + b0;
    float skA[DDEG], skB[DDEG];
    #pragma unroll
    for (int k = 0; k < DDEG; ++k) { skA[k] = 0.f; skB[k] = 0.f; }
    float mx = 0.f;
    float xa0 = xp[0],               xa1 = xp[(size_t)1 * NF];
    float xa2 = xp[(size_t)2 * NF],  xa3 = xp[(size_t)3 * NF];
    float ya0 = yp[0], ya1 = yp[1], ya2 = yp[2], ya3 = yp[3];
    for (int r = 0; r < rows; r += 4) {
      const int rn = (r + 4 < rows) ? (r + 4) : r;   // clamped prefetch
      float xb0 = xp[(size_t)(rn + 0) * NF];
      float xb1 = xp[(size_t)(rn + 1) * NF];
      float xb2 = xp[(size_t)(rn + 2) * NF];
      float xb3 = xp[(size_t)(rn + 3) * NF];
      float yb0 = yp[rn + 0], yb1 = yp[rn + 1];
      float yb2 = yp[rn + 2], yb3 = yp[rn + 3];
      mx = fmaxf(mx, fmaxf(fmaxf(fabsf(xa0), fabsf(xa1)),
                           fmaxf(fabsf(xa2), fabsf(xa3))));
      float h0 = xa0 * INVX, h1 = xa1 * INVX, h2 = xa2 * INVX, h3 = xa3 * INVX;
      float d0 = h0 + h0, d1 = h1 + h1, d2 = h2 + h2, d3 = h3 + h3;
      float m0 = 1.f, m1 = 1.f, m2 = 1.f, m3 = 1.f;   // T_{k-1}
      float c0 = h0, c1 = h1, c2 = h2, c3 = h3;       // T_k
      skA[0] = fmaf(ya0, h0, skA[0]); skA[0] = fmaf(ya1, h1, skA[0]);
      skB[0] = fmaf(ya2, h2, skB[0]); skB[0] = fmaf(ya3, h3, skB[0]);
      #pragma unroll
      for (int k = 2; k <= DDEG; ++k) {
        float n0 = fmaf(d0, c0, -m0), n1 = fmaf(d1, c1, -m1);
        float n2 = fmaf(d2, c2, -m2), n3 = fmaf(d3, c3, -m3);
        skA[k-1] = fmaf(ya0, n0, skA[k-1]); skA[k-1] = fmaf(ya1, n1, skA[k-1]);
        skB[k-1] = fmaf(ya2, n2, skB[k-1]); skB[k-1] = fmaf(ya3, n3, skB[k-1]);
        m0 = c0; c0 = n0;  m1 = c1; c1 = n1;
        m2 = c2; c2 = n2;  m3 = c3; c3 = n3;
      }
      xa0 = xb0; xa1 = xb1; xa2 = xb2; xa3 = xb3;
      ya0 = yb0; ya1 = yb1; ya2 = yb2; ya3 = yb3;
    }
    #pragma unroll
    for (int m = 1; m < 64; m <<= 1) mx = fmaxf(mx, __shfl_xor(mx, m));
    if ((t & 63) == 0)
      atomicMax(reinterpret_cast<unsigned int*>(&wsf[1]), __float_as_uint(mx));
    // plain vector stores: n*28 floats = n*112 B, 16B-aligned (112 = 7*16)
    float* dst = pmom + (size_t)blockIdx.x * 7168 + n * DDEG;
    #pragma unroll
    for (int q = 0; q < 7; ++q)
      *reinterpret_cast<float4*>(dst + q * 4) =
          make_float4(skA[q*4+0] + skB[q*4+0], skA[q*4+1] + skB[q*4+1],
                      skA[q*4+2] + skB[q*4+2], skA[q*4+3] + skB[q*4+3]);
  } else {
    // ---- coefficient path: thread = (n,h); Chebyshev interp of tanh -------
    const int id = (blockIdx.x - nblkm) * 256 + t;   // 0..8191 = n*32+h
    const float a   = W1[id];
    const float b   = b1[id];
    const float w2a = fabsf(W2[id]);
    const float aX  = a * XFIX;
    float cacc[NNODE];
    #pragma unroll
    for (int k = 0; k < NNODE; ++k) cacc[k] = 0.f;
    for (int j = 0; j < NNODE; ++j) {
      float th = (j + 0.5f) * (float)(M_PI / (double)NNODE);
      float tj = __cosf(th);
      float u  = fmaf(aX, tj, b);
      float f  = 1.f - 2.f * frcp(fexp2(K2C * u) + 1.f);   // exact tanh
      float t2 = tj + tj;
      float Tm = 1.f, Tc = tj;
      cacc[0] += f;
      cacc[1] = fmaf(f, tj, cacc[1]);
      #pragma unroll
      for (int k = 2; k < NNODE; ++k) {
        float Tn = fmaf(t2, Tc, -Tm);
        cacc[k] = fmaf(f, Tn, cacc[k]);
        Tm = Tc; Tc = Tn;
      }
    }
    const float sc = 2.0f / (float)NNODE;
    cws[id] = cacc[0] * (1.0f / (float)NNODE);             // c_0
    #pragma unroll
    for (int k = 1; k <= DDEG; ++k) cws[k * 8192 + id] = cacc[k] * sc;
    float tail = 0.f;
    #pragma unroll
    for (int k = DDEG + 1; k < NNODE; ++k) tail += fabsf(cacc[k]) * sc;
    w2eps[id] = w2a * fmaf(3.0f, tail, 3e-3f);             // |W2|*eps
  }
}

// ---------------- 2-stage deterministic moment reduce ------------------------
// Stage A: 16 j-chunks x 28 t-chunks = 448 blocks. Block (jc,tc) sums slices
// [jc*chunk, jc*chunk+chunk) for its 256 t-values and writes IN-PLACE to slice
// jc*chunk (within its own read set; other blocks touch disjoint rows/cols).
__global__ __launch_bounds__(256) void mreduceA_kernel(float* __restrict__ wsf,
                                                       int nblkm)
{
  const int tc = blockIdx.x % 28;
  const int jc = blockIdx.x / 28;
  const int chunk = nblkm >> 4;                   // nblkm/16, multiple of 4
  const int t = tc * 256 + threadIdx.x;           // 0..7167
  float* p = wsf + 253952;
  const float* src = p + (size_t)jc * chunk * 7168 + t;
  float s0 = 0.f, s1 = 0.f, s2 = 0.f, s3 = 0.f;
  for (int i = 0; i < chunk; i += 4) {
    s0 += src[(size_t)i * 7168];
    s1 += src[(size_t)(i + 1) * 7168];
    s2 += src[(size_t)(i + 2) * 7168];
    s3 += src[(size_t)(i + 3) * 7168];
  }
  p[(size_t)jc * chunk * 7168 + t] = (s0 + s1) + (s2 + s3);
}

// Stage B: 28 blocks; S[t] = sum over the 16 stage-A slices (fixed order).
__global__ __launch_bounds__(256) void mreduceB_kernel(float* __restrict__ wsf,
                                                       int nblkm)
{
  const int t = blockIdx.x * 256 + threadIdx.x;   // 28 blocks -> 7168
  const int chunk = nblkm >> 4;
  const float* p = wsf + 253952 + t;
  float s = 0.f;
  for (int jc = 0; jc < 16; ++jc) s += p[(size_t)jc * chunk * 7168];
  wsf[256 + t] = s;
}

// ---------------- combine1: p~ and cert per n --------------------------------
__global__ __launch_bounds__(256) void combine1_kernel(
    const float* __restrict__ W2, const float* __restrict__ b2,
    float* __restrict__ wsf)
{
  const int t = threadIdx.x;
  __shared__ float shv[2];
  if (t < 64) {                                  // block-local Sy reduction
    float a = wsf[8 + t], bb = wsf[72 + t];
    #pragma unroll
    for (int m = 1; m < 64; m <<= 1) {
      a  += __shfl_xor(a, m);
      bb += __shfl_xor(bb, m);
    }
    if (t == 0) { shv[0] = a; shv[1] = bb; }
  }
  __syncthreads();
  const float Sy  = shv[0];
  const float SyA = shv[1];
  const int h = t & 31, ng = t >> 5;
  const int n = blockIdx.x * 8 + ng;             // 32 blocks x 8 n
  const int id = n * HID + h;
  const float* S     = wsf + 256;
  const float* cws   = wsf + 8192;
  const float* w2eps = wsf + 245760;
  float T = cws[id] * Sy;                        // c_0 * S_0 (S_0 = sum y)
  #pragma unroll
  for (int k = 1; k <= DDEG; ++k)
    T = fmaf(cws[k * 8192 + id], S[n * DDEG + k - 1], T);
  float acc = W2[id] * T;
  float e   = w2eps[id];
  #pragma unroll
  for (int m = 1; m < 32; m <<= 1) {             // reduce over h (32 lanes)
    acc += __shfl_xor(acc, m);
    e   += __shfl_xor(e, m);
  }
  if (h == 0) {
    wsf[7424 + n] = ALPHA_BF - fmaf(b2[n], Sy, acc);   // p~
    wsf[7680 + n] = fmaf(e, SyA, 128.0f);              // cert (+fp slack)
  }
}

// ---------------- combine2: certified flag -----------------------------------
__global__ __launch_bounds__(256) void combine2_kernel(float* __restrict__ wsf)
{
  const int t = threadIdx.x;
  float v = wsf[7424 + t] - wsf[7680 + t];
  int ok = (v >= 0.f) ? 1 : 0;                   // NaN -> 0
  __shared__ int smi[256];
  smi[t] = ok;
  __syncthreads();
  for (int off = 128; off > 0; off >>= 1) {
    if (t < off) smi[t] = smi[t] & smi[t + off];
    __syncthreads();
  }
  if (t == 0) {
    float Xo = __uint_as_float(*reinterpret_cast<unsigned int*>(&wsf[1]));
    wsf[0] = (smi[0] && (Xo <= XFIX)) ? 1.f : 0.f;
  }
}

// ---------------- zero-path output writer ------------------------------------
__global__ __launch_bounds__(256) void zwrite_kernel(const float* __restrict__ wsf,
                                                     float* __restrict__ out)
{
  if (wsf[0] < 0.5f) return;
  int i = blockIdx.x * 256 + threadIdx.x;        // 257 blocks = 65792
  if (i < BATCHN + NF) out[i] = 0.f;
}

// ================= exact fallback path (flagA==0 only) =======================
__global__ __launch_bounds__(256, 2) void zty_kernel(
    const float* __restrict__ x, const float* __restrict__ y,
    const float* __restrict__ W1, const float* __restrict__ b1,
    const float* __restrict__ W2, const float* __restrict__ b2,
    const float* __restrict__ flag, float* __restrict__ part, int rows)
{
  if (flag[0] >= 0.5f) return;
  const int n = threadIdx.x;
  const int blk = blockIdx.x;
  float w1s[HID], b1s[HID], w2[HID];
  float base = b2[n];
  #pragma unroll
  for (int h = 0; h < HID; ++h) {
    w1s[h] = W1[n * HID + h] * K2C;
    b1s[h] = b1[n * HID + h] * K2C;
    w2[h]  = W2[n * HID + h];
    base  += w2[h];
  }
  const int b0 = blk * rows;
  const float* xp = x + (size_t)b0 * NF + n;
  float xv = xp[0];
  float yv = y[b0];
  float zty = 0.f;
  for (int r = 0; r < rows; ++r) {
    int rn = (r + 1 < rows) ? (r + 1) : r;
    float xnext = xp[(size_t)rn * NF];
    float ynext = y[b0 + rn];
    float a0 = 0.f, a1 = 0.f, a2 = 0.f, a3 = 0.f;
    #pragma unroll
    for (int h = 0; h < HID; h += 4) {
      float u0 = fmaf(xv, w1s[h + 0], b1s[h + 0]);
      float u1 = fmaf(xv, w1s[h + 1], b1s[h + 1]);
      float u2 = fmaf(xv, w1s[h + 2], b1s[h + 2]);
      float u3 = fmaf(xv, w1s[h + 3], b1s[h + 3]);
      float e0 = fexp2(u0), e1 = fexp2(u1), e2 = fexp2(u2), e3 = fexp2(u3);
      a0 = fmaf(w2[h + 0], frcp(e0 + 1.f), a0);
      a1 = fmaf(w2[h + 1], frcp(e1 + 1.f), a1);
      a2 = fmaf(w2[h + 2], frcp(e2 + 1.f), a2);
      a3 = fmaf(w2[h + 3], frcp(e3 + 1.f), a3);
    }
    float z = fmaf(-2.f, (a0 + a1) + (a2 + a3), base);
    zty = fmaf(z, yv, zty);
    xv = xnext; yv = ynext;
  }
  part[(size_t)blk * NF + n] = zty;
}

__global__ __launch_bounds__(256) void reduce1(const float* __restrict__ flag,
                                               const float* __restrict__ part,
                                               float* __restrict__ part2,
                                               int chunks)
{
  if (flag[0] >= 0.5f) return;
  int n = threadIdx.x, j = blockIdx.x;
  float s = 0.f;
  for (int k = 0; k < chunks; ++k) s += part[(size_t)(j * chunks + k) * NF + n];
  part2[(size_t)j * NF + n] = s;
}

__global__ __launch_bounds__(256) void reduce2(const float* __restrict__ flag,
                                               const float* __restrict__ part2,
                                               float* __restrict__ p)
{
  if (flag[0] >= 0.5f) return;
  int n = threadIdx.x;
  float s = 0.f;
  for (int k = 0; k < 64; ++k) s += part2[(size_t)k * NF + n];
  p[n] = ALPHA_BF - s;
}

__global__ __launch_bounds__(256) void qinit(const float* __restrict__ flag,
                                             float* __restrict__ Q)
{
  if (flag[0] >= 0.5f) return;
  int idx = blockIdx.x * 256 + threadIdx.x;
  int i = idx >> 8, j = idx & 255;
  Q[idx] = (i == j) ? JITTERF : 0.f;
}

__global__ __launch_bounds__(256) void qacc(
    const float* __restrict__ x,
    const float* __restrict__ W1, const float* __restrict__ b1,
    const float* __restrict__ W2, const float* __restrict__ b2,
    const float* __restrict__ flag, float* __restrict__ Q)
{
  if (flag[0] >= 0.5f) return;
  __shared__ float zsh[64 * NF];                 // 64 KiB
  const int t = threadIdx.x;
  float w1s[HID], b1s[HID], w2[HID];
  float base = b2[t];
  #pragma unroll
  for (int h = 0; h < HID; ++h) {
    w1s[h] = W1[t * HID + h] * K2C;
    b1s[h] = b1[t * HID + h] * K2C;
    w2[h]  = W2[t * HID + h];
    base  += w2[h];
  }
  const int b0 = blockIdx.x * 64;
  for (int r = 0; r < 64; ++r) {
    float xv = x[(size_t)(b0 + r) * NF + t];
    float acc = 0.f;
    #pragma unroll
    for (int h = 0; h < HID; ++h) {
      float u = fmaf(xv, w1s[h], b1s[h]);
      acc = fmaf(w2[h], frcp(fexp2(u) + 1.f), acc);
    }
    zsh[r * NF + t] = fmaf(-2.f, acc, base);
  }
  __syncthreads();
  for (int j = 0; j < NF; ++j) {
    float s = 0.f;
    for (int r = 0; r < 64; ++r) s += zsh[r * NF + t] * zsh[r * NF + j];
    atomicAdd(&Q[t * NF + j], s);
  }
}

__global__ __launch_bounds__(256) void solver_kernel(
    const float* __restrict__ flag, const float* __restrict__ p,
    const float* __restrict__ Q, float* __restrict__ L, float* __restrict__ Qe,
    float* __restrict__ lamg, float* __restrict__ dout_lam)
{
  if (flag[0] >= 0.5f) return;
  const int t = threadIdx.x;
  __shared__ float sm[NF];
  __shared__ float lam_s[NF];
  for (int i = 0; i < NF; ++i) L[i * NF + t] = (t <= i) ? Q[i * NF + t] : 0.f;
  __syncthreads();
  for (int k = 0; k < NF; ++k) {                 // right-looking Cholesky
    if (t == 0) L[k * NF + k] = sqrtf(L[k * NF + k]);
    __syncthreads();
    float lkk = L[k * NF + k];
    if (t > k) L[t * NF + k] /= lkk;
    __syncthreads();
    if (t > k) {
      float ltk = L[t * NF + k];
      for (int i = k + 1; i <= t; ++i) L[t * NF + i] -= ltk * L[i * NF + k];
    }
    __syncthreads();
  }
  for (int i = 0; i < NF; ++i) {                 // Qe = L L^T
    int m = (i < t) ? i : t;
    float s = 0.f;
    for (int k = 0; k <= m; ++k) s += L[i * NF + k] * L[t * NF + k];
    Qe[i * NF + t] = s;
  }
  __syncthreads();
  lam_s[t] = 1.f;
  __syncthreads();
  float lmax = 1.f;
  for (int it = 0; it < 256; ++it) {             // power iteration
    float s = 0.f;
    for (int k = 0; k < NF; ++k) s += Qe[t * NF + k] * lam_s[k];
    sm[t] = s * s;
    __syncthreads();
    for (int off = 128; off > 0; off >>= 1) {
      if (t < off) sm[t] += sm[t + off];
      __syncthreads();
    }
    float nrm = sqrtf(sm[0]);
    __syncthreads();
    lam_s[t] = s / nrm;
    lmax = nrm;
    __syncthreads();
  }
  float step = 1.0f / lmax;
  lam_s[t] = 0.f;
  __syncthreads();
  float pv = p[t];
  for (int it = 0; it < QP_ITERS_N; ++it) {
    float s = 0.f;
    for (int k = 0; k < NF; ++k) s += Qe[t * NF + k] * lam_s[k];
    float ln = fmaxf(lam_s[t] - step * (s + pv), 0.f);
    __syncthreads();
    lam_s[t] = ln;
    __syncthreads();
  }
  dout_lam[t] = lam_s[t];
  lamg[t] = lam_s[t];
}

__global__ __launch_bounds__(256) void yhat_kernel(
    const float* __restrict__ x,
    const float* __restrict__ W1, const float* __restrict__ b1,
    const float* __restrict__ W2, const float* __restrict__ b2,
    const float* __restrict__ flag, const float* __restrict__ lamg,
    float* __restrict__ yhat)
{
  if (flag[0] >= 0.5f) return;
  const int b = blockIdx.x * 256 + threadIdx.x;
  __shared__ float lam_s[NF];
  lam_s[threadIdx.x] = lamg[threadIdx.x];
  __syncthreads();
  float acc = 0.f;
  for (int n = 0; n < NF; ++n) {
    float xv = x[(size_t)b * NF + n];
    float zacc = 0.f, base = b2[n];
    for (int h = 0; h < HID; ++h) {
      float w2h = W2[n * HID + h];
      base += w2h;
      float u = fmaf(xv, W1[n * HID + h] * K2C, b1[n * HID + h] * K2C);
      zacc = fmaf(w2h, frcp(fexp2(u) + 1.f), zacc);
    }
    acc = fmaf(fmaf(-2.f, zacc, base), lam_s[n], acc);
  }
  yhat[b] = acc;
}

// ---------------- host launcher ---------------------------------------------
extern "C" void kernel_launch(void* const* d_in, const int* in_sizes, int n_in,
                              void* d_out, int out_size, void* d_ws, size_t ws_size,
                              hipStream_t stream) {
  const float* x  = (const float*)d_in[0];
  const float* y  = (const float*)d_in[1];
  const float* W1 = (const float*)d_in[2];
  const float* b1 = (const float*)d_in[3];
  const float* W2 = (const float*)d_in[4];
  const float* b2 = (const float*)d_in[5];
  float* out = (float*)d_out;            // [0,65536): y_hat ; [65536,65792): lam
  float* ws  = (float*)d_ws;

  // size tiers (deterministic in ws_size): pmom overlays fallback buffers
  int nblkm = 1024, nblk = 2048;
  auto fb_floats = [](int bk) -> size_t {
    return (size_t)bk * NF + 16384 + 256 + 256 + 3 * 65536;
  };
  auto fits = [&](int bm, int bk) -> bool {
    size_t pm = (size_t)bm * 7168;
    size_t fb = fb_floats(bk);
    size_t tot = 253952 + (pm > fb ? pm : fb);
    return tot * 4 <= ws_size;
  };
  while (nblkm > 64 && !fits(nblkm, nblk)) nblkm >>= 1;
  if (!fits(nblkm, nblk)) nblk = 1024;
  const int rows_m = BATCHN / nblkm;
  const int rows_f = BATCHN / nblk;
  const int chunks = nblk / 64;

  float* flagA  = ws;                    // ws[0]
  float* ovl    = ws + 253952;           // pmom / fallback overlay
  float* part   = ovl;
  float* part2  = part + (size_t)nblk * NF;
  float* p_ex   = part2 + 16384;
  float* lam    = p_ex + 256;
  float* Q      = lam + 256;
  float* L      = Q + 65536;
  float* Qe     = L + 65536;

  // fast certified path (atomic-free except order-exact atomicMax on |x|)
  zero_kernel<<<1, 256, 0, stream>>>(ws);
  ysum_kernel<<<64, 256, 0, stream>>>(y, ws);
  momentcoeff_kernel<<<nblkm + 32, 256, 0, stream>>>(x, y, W1, b1, W2, ws,
                                                     nblkm, rows_m);
  mreduceA_kernel<<<448, 256, 0, stream>>>(ws, nblkm);
  mreduceB_kernel<<<28, 256, 0, stream>>>(ws, nblkm);
  combine1_kernel<<<32, 256, 0, stream>>>(W2, b2, ws);
  combine2_kernel<<<1, 256, 0, stream>>>(ws);
  zwrite_kernel<<<257, 256, 0, stream>>>(ws, out);

  // exact fallback (flag-guarded; near-free when certified)
  zty_kernel<<<nblk, 256, 0, stream>>>(x, y, W1, b1, W2, b2, flagA, part, rows_f);
  reduce1<<<64, 256, 0, stream>>>(flagA, part, part2, chunks);
  reduce2<<<1, 256, 0, stream>>>(flagA, part2, p_ex);
  qinit<<<256, 256, 0, stream>>>(flagA, Q);
  qacc<<<1024, 256, 0, stream>>>(x, W1, b1, W2, b2, flagA, Q);
  solver_kernel<<<1, 256, 0, stream>>>(flagA, p_ex, Q, L, Qe, lam, out + BATCHN);
  yhat_kernel<<<BATCHN / 256, 256, 0, stream>>>(x, W1, b1, W2, b2, flagA, lam, out);
}